// Round 16
// baseline (1332.986 us; speedup 1.0000x reference)
//
#include <hip/hip_runtime.h>
#include <math.h>

#define HH  64
#define TT  2048
#define IND 7
#define NT  512          // 8 waves: 4 L0 + 4 L1, 2 per SIMD

typedef _Float16 half_t;
typedef _Float16 h2v __attribute__((ext_vector_type(2)));
typedef _Float16 h8v __attribute__((ext_vector_type(8)));
typedef unsigned int u2v __attribute__((ext_vector_type(2)));

#define LOG2E 1.44269504088896f

// constant-index h2v slice of an h8v: exact VGPR subregister
#define S2C(V, I) __builtin_shufflevector(V, V, 2*(I), 2*(I)+1)

// f16 dot2 with fp32 accumulate
__device__ __forceinline__ float fdot2(h2v a, h2v b, float c) {
#if __has_builtin(__builtin_amdgcn_fdot2)
    return __builtin_amdgcn_fdot2(a, b, c, false);
#else
    return fmaf((float)a.x, (float)b.x, fmaf((float)a.y, (float)b.y, c));
#endif
}

__device__ __forceinline__ float exp2_fast(float x) {
#if __has_builtin(__builtin_amdgcn_exp2f)
    return __builtin_amdgcn_exp2f(x);
#else
    return exp2f(x);
#endif
}
__device__ __forceinline__ float rcp_fast(float x) {
#if __has_builtin(__builtin_amdgcn_rcpf)
    return __builtin_amdgcn_rcpf(x);
#else
    return __fdividef(1.0f, x);
#endif
}

// partner across lane^32 (VALU pipe, v_permlane32_swap; selection verified r9-r15)
__device__ __forceinline__ float partner32(float x, int b5) {
#if __has_builtin(__builtin_amdgcn_permlane32_swap)
    u2v r = __builtin_amdgcn_permlane32_swap(__float_as_uint(x), __float_as_uint(x), false, false);
    return b5 ? __uint_as_float(r.x) : __uint_as_float(r.y);
#else
    return __shfl_xor(x, 32);
#endif
}
// partner across lane^16 (v_permlane16_swap, mirrored selection; shfl fallback)
__device__ __forceinline__ float partner16(float x, int b4) {
#if __has_builtin(__builtin_amdgcn_permlane16_swap)
    u2v r = __builtin_amdgcn_permlane16_swap(__float_as_uint(x), __float_as_uint(x), false, false);
    return b4 ? __uint_as_float(r.x) : __uint_as_float(r.y);
#else
    return __shfl_xor(x, 16);
#endif
}

// 2-stage all-VALU reduce over lane bits 4 then 5
__device__ __forceinline__ float qreduce(float pr, int b4, int b5) {
    float s1 = pr + partner16(pr, b4);
    return s1 + partner32(s1, b5);
}

// sigmoid with pre-scaled (log2e) argument
__device__ __forceinline__ float sig2(float ahat) {
    return rcp_fast(1.0f + exp2_fast(-ahat));
}
__device__ __forceinline__ float tanh2(float c) {
    float e = exp2_fast(c * (-2.0f * LOG2E));
    return fmaf(2.0f, rcp_fast(1.0f + e), -1.0f);
}

// 4 f16-dot2 of weight block (W)[0..3] against the 4 h2v slices of h8v H
#define DOT4(ACC, W, H) \
    ACC = fdot2((W)[0], S2C(H, 0), ACC); \
    ACC = fdot2((W)[1], S2C(H, 1), ACC); \
    ACC = fdot2((W)[2], S2C(H, 2), ACC); \
    ACC = fdot2((W)[3], S2C(H, 3), ACC);

__global__ __launch_bounds__(NT) __attribute__((amdgpu_waves_per_eu(2, 2)))
void lstm2_fused(
    const float* __restrict__ x,     // (B,7,2048)
    const float* __restrict__ Wih0,  // (256,7)
    const float* __restrict__ Whh0,  // (256,64)
    const float* __restrict__ bih0, const float* __restrict__ bhh0,
    const float* __restrict__ Wih1,  // (256,64)
    const float* __restrict__ Whh1,  // (256,64)
    const float* __restrict__ bih1, const float* __restrict__ bhh1,
    const float* __restrict__ W1,    // (10,64)
    const float* __restrict__ b1v,   // (10)
    const float* __restrict__ gmma, const float* __restrict__ beta,
    const float* __restrict__ rm,   const float* __restrict__ rv,
    const float* __restrict__ W2,   // (1,10)
    const float* __restrict__ b2,   // (1)
    float* __restrict__ out)         // (B,1)
{
    const int b    = blockIdx.x;
    const int tid  = threadIdx.x;
    const int wave = tid >> 6;       // 0-3: L0   4-7: L1
    const int lane = tid & 63;
    const int ul   = lane & 15;                  // unit-low 4 bits
    const int j    = ((wave & 3) << 4) | ul;     // hidden unit 0..63
    const int b4   = (lane >> 4) & 1;            // split bit 0 (permlane16)
    const int b5   = lane >> 5;                  // split bit 1 (permlane32)
    const int qq   = lane >> 4;                  // 16-lane group 0..3
    const bool pub = (qq == 0);                  // lanes 0-15 publish

    __shared__ __align__(16) half_t xTh[TT][8];       // 32 KB, f16 x, [7]=0 pad
    // [p][layer][unit] with 80-unit stride: layer offset 160B = 32 mod 128
    // -> the 4 uniform 16-lane-group reads hit disjoint bank quads
    __shared__ __align__(16) half_t hbuf[2][2][80];
    __shared__ float yv[10];

    // ---- stage x[b] transposed, converted to f16 ----
    {
        const float* xg = x + (size_t)b * (IND * TT);
        for (int i = tid; i < IND * TT; i += NT) {
            int d = i >> 11;
            int t = i & (TT - 1);
            xTh[t][d] = (half_t)xg[i];
        }
        for (int t = tid; t < TT; t += NT) xTh[t][7] = (half_t)0.0f;
        if (tid < 160) {
            ((half_t*)hbuf)[tid]       = (half_t)0.0f;
            ((half_t*)hbuf)[160 + tid] = (half_t)0.0f;
        }
    }

    __syncthreads();

    if (wave < 4) {
        // ===== LAYER-0 (4 waves): lane = (unit, k-quarter qq), 4 gates in-lane =====
        // quarter qq covers k in [16*qq, 16*qq+16); x weights live on qq==3 lanes
        h2v wh[4][8];    // Whh0 quarter-rows, 4 gates (16 f16 each)
        h2v xw[4][4];    // Wih0 rows, nonzero only on qq==3 lanes
        float bg[4];
        #pragma unroll
        for (int s = 0; s < 4; ++s) {
            const int g = (s << 6) | j;
            const float sc = (s == 2) ? 2.0f * LOG2E : LOG2E;
            const float* pw = Whh0 + g * HH + 16 * qq;
            #pragma unroll
            for (int r = 0; r < 8; ++r)
                wh[s][r] = h2v{(half_t)(pw[2*r] * sc), (half_t)(pw[2*r+1] * sc)};
            float t8[8];
            #pragma unroll
            for (int d = 0; d < 8; ++d)
                t8[d] = (d < IND && qq == 3) ? Wih0[g * IND + d] * sc : 0.0f;
            #pragma unroll
            for (int r = 0; r < 4; ++r)
                xw[s][r] = h2v{(half_t)t8[2*r], (half_t)t8[2*r+1]};
            bg[s] = (qq == 0) ? (bih0[g] + bhh0[g]) * sc : 0.0f;
        }

        float c0 = 0.0f;

        for (int tick = 0; tick <= TT; ++tick) {
            const int p = tick & 1;
            if (tick < TT) {
                // group-uniform broadcast reads: banks disjoint across groups
                const h8v* hp = (const h8v*)&hbuf[p ^ 1][0][16 * qq];
                h8v H0 = hp[0], H1 = hp[1];
                h8v XV = *((const h8v*)&xTh[tick][0]);    // wave-uniform
                float fr[4];
                #pragma unroll
                for (int s = 0; s < 4; ++s) {
                    float a = bg[s], bb = 0.0f;
                    DOT4(a,  &wh[s][0], H0)
                    DOT4(bb, &wh[s][4], H1)
                    DOT4(a,  &xw[s][0], XV)
                    fr[s] = a + bb;
                }
                float fi = qreduce(fr[0], b4, b5);
                float ff = qreduce(fr[1], b4, b5);
                float fg = qreduce(fr[2], b4, b5);
                float fo = qreduce(fr[3], b4, b5);
                float iv = sig2(fi);
                float fv = sig2(ff);
                float gv = fmaf(2.0f, sig2(fg), -1.0f);
                float ov = sig2(fo);
                c0 = fmaf(fv, c0, iv * gv);
                float hn = ov * tanh2(c0);
                if (pub) hbuf[p][0][j] = (half_t)hn;
            }
            __syncthreads();
        }
    } else {
        // ===== LAYER-1 (4 waves): lane = (unit, matrix mh x k-half kh), one tick behind =====
        const int mh = b4;          // 0: Wih1@h0, 1: Whh1@h1
        const int kh = b5;          // k-half within the matrix
        h2v wt[4][16];   // one matrix's k-half: 32 f16 per gate
        float bg[4];
        const float* WB = mh ? Whh1 : Wih1;
        #pragma unroll
        for (int s = 0; s < 4; ++s) {
            const int g = (s << 6) | j;
            const float sc = (s == 2) ? 2.0f * LOG2E : LOG2E;
            const float* pw = WB + g * HH + 32 * kh;
            #pragma unroll
            for (int r = 0; r < 16; ++r)
                wt[s][r] = h2v{(half_t)(pw[2*r] * sc), (half_t)(pw[2*r+1] * sc)};
            bg[s] = (qq == 0) ? (bih1[g] + bhh1[g]) * sc : 0.0f;
        }

        float c1 = 0.0f;

        for (int tick = 0; tick <= TT; ++tick) {
            const int p = tick & 1;
            if (tick > 0) {
                // group-uniform reads; mh picks layer (banks offset by 160B pad)
                const h8v* hp = (const h8v*)&hbuf[p ^ 1][mh][32 * kh];
                h8v H0 = hp[0], H1 = hp[1], H2 = hp[2], H3 = hp[3];
                float fr[4];
                #pragma unroll
                for (int s = 0; s < 4; ++s) {
                    float a = bg[s], bb = 0.0f;
                    DOT4(a,  &wt[s][0],  H0)
                    DOT4(bb, &wt[s][4],  H1)
                    DOT4(a,  &wt[s][8],  H2)
                    DOT4(bb, &wt[s][12], H3)
                    fr[s] = a + bb;
                }
                float fi = qreduce(fr[0], b4, b5);
                float ff = qreduce(fr[1], b4, b5);
                float fg = qreduce(fr[2], b4, b5);
                float fo = qreduce(fr[3], b4, b5);
                float iv = sig2(fi);
                float fv = sig2(ff);
                float gv = fmaf(2.0f, sig2(fg), -1.0f);
                float ov = sig2(fo);
                c1 = fmaf(fv, c1, iv * gv);
                float hn = ov * tanh2(c1);
                if (pub) hbuf[p][1][j] = (half_t)hn;
            }
            __syncthreads();
        }
    }

    // h1(TT-1) was stored at tick TT into hbuf[0][1][*]
    if (tid < 10) {
        float y = b1v[tid];
        #pragma unroll
        for (int k = 0; k < HH; ++k) y += W1[tid * HH + k] * (float)hbuf[0][1][k];
        y = (y - rm[tid]) * rsqrtf(rv[tid] + 1e-5f) * gmma[tid] + beta[tid];
        y = fmaxf(y, 0.0f);
        yv[tid] = y * W2[tid];
    }
    __syncthreads();
    if (tid == 0) {
        float sacc = b2[0];
        #pragma unroll
        for (int k = 0; k < 10; ++k) sacc += yv[k];
        out[b] = sacc;
    }
}

extern "C" void kernel_launch(void* const* d_in, const int* in_sizes, int n_in,
                              void* d_out, int out_size, void* d_ws, size_t ws_size,
                              hipStream_t stream) {
    const float* x    = (const float*)d_in[0];
    const float* Wih0 = (const float*)d_in[1];
    const float* Whh0 = (const float*)d_in[2];
    const float* bih0 = (const float*)d_in[3];
    const float* bhh0 = (const float*)d_in[4];
    const float* Wih1 = (const float*)d_in[5];
    const float* Whh1 = (const float*)d_in[6];
    const float* bih1 = (const float*)d_in[7];
    const float* bhh1 = (const float*)d_in[8];
    const float* W1   = (const float*)d_in[9];
    const float* b1   = (const float*)d_in[10];
    const float* gmma = (const float*)d_in[11];
    const float* beta = (const float*)d_in[12];
    const float* rm   = (const float*)d_in[13];
    const float* rv   = (const float*)d_in[14];
    const float* W2   = (const float*)d_in[15];
    const float* b2   = (const float*)d_in[16];

    const int B = in_sizes[0] / (IND * TT);   // 256

    lstm2_fused<<<dim3(B), dim3(NT), 0, stream>>>(
        x, Wih0, Whh0, bih0, bhh0, Wih1, Whh1, bih1, bhh1,
        W1, b1, gmma, beta, rm, rv, W2, b2, (float*)d_out);
}

// Round 17
// 1039.651 us; speedup vs baseline: 1.2821x; 1.2821x over previous
//
#include <hip/hip_runtime.h>
#include <math.h>

#define HH  64
#define TT  2048
#define IND 7
#define NT  256          // 4 waves: 2 L0 + 2 L1, one per SIMD

typedef _Float16 half_t;
typedef _Float16 h2v __attribute__((ext_vector_type(2)));
typedef _Float16 h8v __attribute__((ext_vector_type(8)));
typedef unsigned int u2v __attribute__((ext_vector_type(2)));

#define LOG2E 1.44269504088896f

// constant-index h2v slice of an h8v: exact VGPR subregister
#define S2C(V, I) __builtin_shufflevector(V, V, 2*(I), 2*(I)+1)

// f16 dot2 with fp32 accumulate
__device__ __forceinline__ float fdot2(h2v a, h2v b, float c) {
#if __has_builtin(__builtin_amdgcn_fdot2)
    return __builtin_amdgcn_fdot2(a, b, c, false);
#else
    return fmaf((float)a.x, (float)b.x, fmaf((float)a.y, (float)b.y, c));
#endif
}

__device__ __forceinline__ float exp2_fast(float x) {
#if __has_builtin(__builtin_amdgcn_exp2f)
    return __builtin_amdgcn_exp2f(x);
#else
    return exp2f(x);
#endif
}
__device__ __forceinline__ float rcp_fast(float x) {
#if __has_builtin(__builtin_amdgcn_rcpf)
    return __builtin_amdgcn_rcpf(x);
#else
    return __fdividef(1.0f, x);
#endif
}

// value held by the lane^32 partner (VALU pipe, v_permlane32_swap; verified r9-r16)
__device__ __forceinline__ float partner32(float x, int kh) {
#if __has_builtin(__builtin_amdgcn_permlane32_swap)
    u2v r = __builtin_amdgcn_permlane32_swap(__float_as_uint(x), __float_as_uint(x), false, false);
    return kh ? __uint_as_float(r.x) : __uint_as_float(r.y);
#else
    return __shfl_xor(x, 32);
#endif
}

// sigmoid / tanh with log2e-pre-scaled weights (verified r13-r16)
__device__ __forceinline__ float sig2(float ahat) {
    return rcp_fast(1.0f + exp2_fast(-ahat));
}
__device__ __forceinline__ float tanh2(float c) {
    float e = exp2_fast(c * (-2.0f * LOG2E));
    return fmaf(2.0f, rcp_fast(1.0f + e), -1.0f);
}

// 4 f16-dot2 of weight block (W)[0..3] against the 4 h2v slices of h8v H
#define DOT4(ACC, W, H) \
    ACC = fdot2((W)[0], S2C(H, 0), ACC); \
    ACC = fdot2((W)[1], S2C(H, 1), ACC); \
    ACC = fdot2((W)[2], S2C(H, 2), ACC); \
    ACC = fdot2((W)[3], S2C(H, 3), ACC);

__global__ __launch_bounds__(NT) __attribute__((amdgpu_waves_per_eu(1, 1)))
void lstm2_fused(
    const float* __restrict__ x,     // (B,7,2048)
    const float* __restrict__ Wih0,  // (256,7)
    const float* __restrict__ Whh0,  // (256,64)
    const float* __restrict__ bih0, const float* __restrict__ bhh0,
    const float* __restrict__ Wih1,  // (256,64)
    const float* __restrict__ Whh1,  // (256,64)
    const float* __restrict__ bih1, const float* __restrict__ bhh1,
    const float* __restrict__ W1,    // (10,64)
    const float* __restrict__ b1v,   // (10)
    const float* __restrict__ gmma, const float* __restrict__ beta,
    const float* __restrict__ rm,   const float* __restrict__ rv,
    const float* __restrict__ W2,   // (1,10)
    const float* __restrict__ b2,   // (1)
    float* __restrict__ out)         // (B,1)
{
    const int b    = blockIdx.x;
    const int tid  = threadIdx.x;
    const int wave = tid >> 6;       // 0,1: L0   2,3: L1
    const int lane = tid & 63;
    const int kh   = lane >> 5;                   // k-half (lane bit 5)
    const int j    = ((wave & 1) << 5) | (lane & 31);  // hidden unit 0..63
    const bool pub = (kh == 0);

    __shared__ __align__(16) half_t xTh[TT][8];   // 32 KB, f16 x, [7]=0 pad
    __shared__ __align__(16) half_t h0r[4][HH];   // h0 ring (lag-2 liveness)
    __shared__ __align__(16) half_t h1r[2][HH];   // h1 double buffer
    __shared__ float yv[10];

    // ---- stage x[b] transposed, converted to f16 ----
    {
        const float* xg = x + (size_t)b * (IND * TT);
        for (int i = tid; i < IND * TT; i += NT) {
            int d = i >> 11;
            int t = i & (TT - 1);
            xTh[t][d] = (half_t)xg[i];
        }
        for (int t = tid; t < TT; t += NT) xTh[t][7] = (half_t)0.0f;
        if (tid < HH) {
            h0r[3][tid] = (half_t)0.0f;   // h0(-1)
            h1r[1][tid] = (half_t)0.0f;   // h1(-1)
        }
    }

    __syncthreads();

    if (wave < 2) {
        // ===== LAYER-0 (2 waves): lane=(unit j, kh); computes h0(t) at tick t =====
        h2v wh[4][16];    // Whh0 k-half rows, 4 gates
        h2v xw[4][4];     // Wih0 rows (kh==1 lanes carry x; kh==0 zeros)
        float bg[4];
        #pragma unroll
        for (int s = 0; s < 4; ++s) {
            const int g = (s << 6) | j;
            const float sc = (s == 2) ? 2.0f * LOG2E : LOG2E;
            const float* pw = Whh0 + g * HH + 32 * kh;
            #pragma unroll
            for (int r = 0; r < 16; ++r)
                wh[s][r] = h2v{(half_t)(pw[2*r] * sc), (half_t)(pw[2*r+1] * sc)};
            float t8[8];
            #pragma unroll
            for (int d = 0; d < 8; ++d)
                t8[d] = (d < IND && kh) ? Wih0[g * IND + d] * sc : 0.0f;
            #pragma unroll
            for (int r = 0; r < 4; ++r)
                xw[s][r] = h2v{(half_t)t8[2*r], (half_t)t8[2*r+1]};
            bg[s] = (kh == 0) ? (bih0[g] + bhh0[g]) * sc : 0.0f;
        }

        float c0 = 0.0f;
        h8v XV = *((const h8v*)&xTh[0][0]);       // prefetched x(t)

        for (int tick = 0; tick <= TT + 1; ++tick) {
            if (tick < TT) {
                const h8v* hp = (const h8v*)&h0r[(tick - 1) & 3][32 * kh];
                h8v H0 = hp[0], H1 = hp[1], H2 = hp[2], H3 = hp[3];
                float fr[4];
                #pragma unroll
                for (int s = 0; s < 4; ++s) {
                    float a0 = bg[s], a1 = 0.f, a2 = 0.f, a3 = 0.f;
                    DOT4(a0, &xw[s][0], XV)           // x first: covers H latency
                    DOT4(a0, &wh[s][0],  H0)
                    DOT4(a1, &wh[s][4],  H1)
                    DOT4(a2, &wh[s][8],  H2)
                    DOT4(a3, &wh[s][12], H3)
                    fr[s] = (a0 + a1) + (a2 + a3);
                }
                float fi = fr[0] + partner32(fr[0], kh);
                float ff = fr[1] + partner32(fr[1], kh);
                float fg = fr[2] + partner32(fr[2], kh);
                float fo = fr[3] + partner32(fr[3], kh);
                float iv = sig2(fi);
                float fv = sig2(ff);
                float gv = fmaf(2.0f, sig2(fg), -1.0f);
                float ov = sig2(fo);
                c0 = fmaf(fv, c0, iv * gv);
                float hn = ov * tanh2(c0);
                if (pub) h0r[tick & 3][j] = (half_t)hn;
                XV = *((const h8v*)&xTh[(tick + 1) & (TT - 1)][0]);
            }
            __syncthreads();
        }
    } else {
        // ===== LAYER-1 (2 waves): lane=(unit j, kh); computes h1(t-2) at tick t =====
        // per-lane: k-half rows of BOTH Wih1 and Whh1, 4 gates (128 VGPR f16)
        h2v wi[4][16], wh[4][16];
        float bg[4];
        #pragma unroll
        for (int s = 0; s < 4; ++s) {
            const int g = (s << 6) | j;
            const float sc = (s == 2) ? 2.0f * LOG2E : LOG2E;
            const float* p0 = Wih1 + g * HH + 32 * kh;
            const float* p1 = Whh1 + g * HH + 32 * kh;
            #pragma unroll
            for (int r = 0; r < 16; ++r) {
                wi[s][r] = h2v{(half_t)(p0[2*r] * sc), (half_t)(p0[2*r+1] * sc)};
                wh[s][r] = h2v{(half_t)(p1[2*r] * sc), (half_t)(p1[2*r+1] * sc)};
            }
            bg[s] = (kh == 0) ? (bih1[g] + bhh1[g]) * sc : 0.0f;
        }

        float c1 = 0.0f;
        h8v P0 = {}, P1 = {}, P2 = {}, P3 = {};   // prefetched h0(t-2) k-half

        for (int tick = 0; tick <= TT + 1; ++tick) {
            if (tick >= 2) {
                // issue the recurrence read FIRST; its latency hides under h0-dots
                const h8v* q = (const h8v*)&h1r[(tick - 3) & 1][32 * kh];
                h8v Q0 = q[0], Q1 = q[1], Q2 = q[2], Q3 = q[3];
                float fr[4];
                #pragma unroll
                for (int s = 0; s < 4; ++s) {
                    float a0 = bg[s], a1 = 0.f, a2 = 0.f, a3 = 0.f;
                    // h0 contribution from registers (no LDS dependency)
                    DOT4(a0, &wi[s][0],  P0)
                    DOT4(a1, &wi[s][4],  P1)
                    DOT4(a2, &wi[s][8],  P2)
                    DOT4(a3, &wi[s][12], P3)
                    // h1 recurrence contribution (waits on Q)
                    DOT4(a0, &wh[s][0],  Q0)
                    DOT4(a1, &wh[s][4],  Q1)
                    DOT4(a2, &wh[s][8],  Q2)
                    DOT4(a3, &wh[s][12], Q3)
                    fr[s] = (a0 + a1) + (a2 + a3);
                }
                float fi = fr[0] + partner32(fr[0], kh);
                float ff = fr[1] + partner32(fr[1], kh);
                float fg = fr[2] + partner32(fr[2], kh);
                float fo = fr[3] + partner32(fr[3], kh);
                float iv = sig2(fi);
                float fv = sig2(ff);
                float gv = fmaf(2.0f, sig2(fg), -1.0f);
                float ov = sig2(fo);
                c1 = fmaf(fv, c1, iv * gv);
                float hn = ov * tanh2(c1);
                if (pub) h1r[tick & 1][j] = (half_t)hn;   // (tick-2)&1 == tick&1
            }
            if (tick >= 1) {
                // prefetch h0(tick-1) for NEXT tick's h0-contribution
                // (written by L0 at tick-1, i.e. before the barrier we passed)
                const h8v* pp = (const h8v*)&h0r[(tick - 1) & 3][32 * kh];
                P0 = pp[0]; P1 = pp[1]; P2 = pp[2]; P3 = pp[3];
            }
            __syncthreads();
        }
    }

    // h1(TT-1) was written at tick TT+1 into h1r[(TT-1)&1] = h1r[1]
    if (tid < 10) {
        float y = b1v[tid];
        #pragma unroll
        for (int k = 0; k < HH; ++k) y += W1[tid * HH + k] * (float)h1r[1][k];
        y = (y - rm[tid]) * rsqrtf(rv[tid] + 1e-5f) * gmma[tid] + beta[tid];
        y = fmaxf(y, 0.0f);
        yv[tid] = y * W2[tid];
    }
    __syncthreads();
    if (tid == 0) {
        float sacc = b2[0];
        #pragma unroll
        for (int k = 0; k < 10; ++k) sacc += yv[k];
        out[b] = sacc;
    }
}

extern "C" void kernel_launch(void* const* d_in, const int* in_sizes, int n_in,
                              void* d_out, int out_size, void* d_ws, size_t ws_size,
                              hipStream_t stream) {
    const float* x    = (const float*)d_in[0];
    const float* Wih0 = (const float*)d_in[1];
    const float* Whh0 = (const float*)d_in[2];
    const float* bih0 = (const float*)d_in[3];
    const float* bhh0 = (const float*)d_in[4];
    const float* Wih1 = (const float*)d_in[5];
    const float* Whh1 = (const float*)d_in[6];
    const float* bih1 = (const float*)d_in[7];
    const float* bhh1 = (const float*)d_in[8];
    const float* W1   = (const float*)d_in[9];
    const float* b1   = (const float*)d_in[10];
    const float* gmma = (const float*)d_in[11];
    const float* beta = (const float*)d_in[12];
    const float* rm   = (const float*)d_in[13];
    const float* rv   = (const float*)d_in[14];
    const float* W2   = (const float*)d_in[15];
    const float* b2   = (const float*)d_in[16];

    const int B = in_sizes[0] / (IND * TT);   // 256

    lstm2_fused<<<dim3(B), dim3(NT), 0, stream>>>(
        x, Wih0, Whh0, bih0, bhh0, Wih1, Whh1, bih1, bhh1,
        W1, b1, gmma, beta, rm, rv, W2, b2, (float*)d_out);
}